// Round 2
// baseline (134.952 us; speedup 1.0000x reference)
//
#include <hip/hip_runtime.h>

// Backflow: out[b] = sum_d det(g[b,d]) * bf[d]
//   g[b,d][i][j] = sum_h h2[b,h]*Wg[h,d,sel[b,i],j] + bg[d,sel[b,i],j]
// B=8192, O=64, E=16, D=16, H=4.
//
// One wave per sample; 4 lanes per determinant (lane owns 4 rows), so all 16
// dets of the sample run simultaneously and every cross-lane broadcast
// (ds_bpermute) is amortized over 16 dets. Pivot search: per-lane max over its
// 4 rows (VALU) + 2 DPP quad_perm max stages (VALU, no LDS pipe). Virtual row
// swaps tracked per-slot; sign via vp != k.

template <int CTRL>
__device__ __forceinline__ float dpp_movf(float v) {
    return __int_as_float(__builtin_amdgcn_update_dpp(
        0, __float_as_int(v), CTRL, 0xF, 0xF, true));
}

__global__ __launch_bounds__(256) void backflow_kernel(
    const float* __restrict__ x,    // (B,64)
    const float* __restrict__ W1,   // (64,4)
    const float* __restrict__ b1,   // (4,)
    const float* __restrict__ W2,   // (4,4)
    const float* __restrict__ b2,   // (4,)
    const float* __restrict__ Wg,   // (4,16,64,16)
    const float* __restrict__ bg,   // (16,64,16)
    const float* __restrict__ bf,   // (16,1)
    float* __restrict__ out,        // (B,)
    int B)
{
    const int lane = threadIdx.x & 63;
    const int wavei = threadIdx.x >> 6;
    const int b    = blockIdx.x * 4 + wavei;
    if (b >= B) return;
    const int d  = lane >> 2;   // det index 0..15
    const int l  = lane & 3;    // lane-in-quad; owns physical rows 4l..4l+3
    const int qb = lane & ~3;   // first lane of this quad

    // ---- occupied-orbital mask ----
    const float xv = x[b * 64 + lane];
    const unsigned long long mask = __ballot(xv != 0.0f);
    const bool empty = ((mask & ~1ull) == 0ull);

    // ---- h1 = relu(x @ W1 + b1): 64-lane butterfly ----
    const float4 w1 = reinterpret_cast<const float4*>(W1)[lane];
    float c0 = xv * w1.x, c1 = xv * w1.y, c2 = xv * w1.z, c3 = xv * w1.w;
    #pragma unroll
    for (int off = 32; off >= 1; off >>= 1) {
        c0 += __shfl_xor(c0, off);
        c1 += __shfl_xor(c1, off);
        c2 += __shfl_xor(c2, off);
        c3 += __shfl_xor(c3, off);
    }
    const float h10 = fmaxf(c0 + b1[0], 0.0f);
    const float h11 = fmaxf(c1 + b1[1], 0.0f);
    const float h12 = fmaxf(c2 + b1[2], 0.0f);
    const float h13 = fmaxf(c3 + b1[3], 0.0f);

    // ---- h2 = relu(h1 @ W2 + b2) ----
    float h2[4];
    #pragma unroll
    for (int j = 0; j < 4; ++j) {
        float v = b2[j];
        v = fmaf(h10, W2[0 * 4 + j], v);
        v = fmaf(h11, W2[1 * 4 + j], v);
        v = fmaf(h12, W2[2 * 4 + j], v);
        v = fmaf(h13, W2[3 * 4 + j], v);
        h2[j] = fmaxf(v, 0.0f);
    }

    // ---- sel for the 4 owned rows: skip 4l set bits, then extract 4 ----
    unsigned long long m = mask;
    if (l >= 1) { m &= m-1; m &= m-1; m &= m-1; m &= m-1; }
    if (l >= 2) { m &= m-1; m &= m-1; m &= m-1; m &= m-1; }
    if (l >= 3) { m &= m-1; m &= m-1; m &= m-1; m &= m-1; }
    const int s0 = m ? (int)__builtin_ctzll(m) : 0; m &= m - 1;
    const int s1 = m ? (int)__builtin_ctzll(m) : 0; m &= m - 1;
    const int s2 = m ? (int)__builtin_ctzll(m) : 0; m &= m - 1;
    const int s3 = m ? (int)__builtin_ctzll(m) : 0;

    // ---- build the 4 owned rows of g[b,d] ----
    float row0[16], row1[16], row2[16], row3[16];
#define BUILD_ROW(RW, SQ) do {                                                   \
    const float* base = Wg + ((size_t)d * 64 + (SQ)) * 16;                       \
    const float4* p0 = reinterpret_cast<const float4*>(base);                    \
    const float4* p1 = reinterpret_cast<const float4*>(base + 16384);            \
    const float4* p2 = reinterpret_cast<const float4*>(base + 32768);            \
    const float4* p3 = reinterpret_cast<const float4*>(base + 49152);            \
    const float4* pb = reinterpret_cast<const float4*>(bg + ((size_t)d * 64 + (SQ)) * 16); \
    _Pragma("unroll")                                                            \
    for (int q = 0; q < 4; ++q) {                                                \
        const float4 a0 = p0[q], a1 = p1[q], a2 = p2[q], a3 = p3[q], ab = pb[q]; \
        RW[q*4+0] = fmaf(h2[0],a0.x, fmaf(h2[1],a1.x, fmaf(h2[2],a2.x, fmaf(h2[3],a3.x, ab.x)))); \
        RW[q*4+1] = fmaf(h2[0],a0.y, fmaf(h2[1],a1.y, fmaf(h2[2],a2.y, fmaf(h2[3],a3.y, ab.y)))); \
        RW[q*4+2] = fmaf(h2[0],a0.z, fmaf(h2[1],a1.z, fmaf(h2[2],a2.z, fmaf(h2[3],a3.z, ab.z)))); \
        RW[q*4+3] = fmaf(h2[0],a0.w, fmaf(h2[1],a1.w, fmaf(h2[2],a2.w, fmaf(h2[3],a3.w, ab.w)))); \
    } } while (0)
    BUILD_ROW(row0, s0);
    BUILD_ROW(row1, s1);
    BUILD_ROW(row2, s2);
    BUILD_ROW(row3, s3);
#undef BUILD_ROW

    // ---- LU with partial pivoting; virtual rows vr0..vr3 per slot ----
    double det  = 1.0;
    float  sign = 1.0f;
    int vr0 = 4*l + 0, vr1 = 4*l + 1, vr2 = 4*l + 2, vr3 = 4*l + 3;

    #pragma unroll
    for (int k = 0; k < 16; ++k) {
        // per-lane candidates (|col k| of still-active owned rows)
        const float a0 = (vr0 >= k) ? fabsf(row0[k]) : -1.0f;
        const float a1 = (vr1 >= k) ? fabsf(row1[k]) : -1.0f;
        const float a2 = (vr2 >= k) ? fabsf(row2[k]) : -1.0f;
        const float a3 = (vr3 >= k) ? fabsf(row3[k]) : -1.0f;
        // local max + first-max slot
        const float mx01 = fmaxf(a0, a1);
        const float mx23 = fmaxf(a2, a3);
        const float lmx  = fmaxf(mx01, mx23);
        int lslot = (a0 >= a1) ? 0 : 1;
        lslot = (mx01 >= mx23) ? lslot : ((a2 >= a3) ? 2 : 3);
        // quad max via DPP (no LDS pipe): xor1 = quad_perm[1,0,3,2]=0xB1, xor2 = [2,3,0,1]=0x4E
        float qmx = fmaxf(lmx, dpp_movf<0xB1>(lmx));
        qmx = fmaxf(qmx, dpp_movf<0x4E>(qmx));
        // argmax lane (lowest lane wins ties -> lowest physical row)
        const unsigned long long bal = __ballot(lmx == qmx);
        const int p = qb + (int)__builtin_ctzll((bal >> qb) & 0xFull);

        const bool own = (lane == p);
        const bool pm0 = own && (lslot == 0);
        const bool pm1 = own && (lslot == 1);
        const bool pm2 = own && (lslot == 2);
        const bool pm3 = own && (lslot == 3);

        // broadcast owner's virtual row index (vp) and pivot value
        const int vloc = pm0 ? vr0 : pm1 ? vr1 : pm2 ? vr2 : vr3;
        const int vp   = __shfl(vloc, p);
        sign = (vp != k) ? -sign : sign;

        const float pl    = pm0 ? row0[k] : pm1 ? row1[k] : pm2 ? row2[k] : row3[k];
        const float pivot = __shfl(pl, p);
        det *= (double)pivot;
        const float pinv = (pivot != 0.0f) ? __builtin_amdgcn_rcpf(pivot) : 0.0f;

        // virtual swap: pivot slot -> k; slot that held k -> vp
        vr0 = pm0 ? k : (vr0 == k ? vp : vr0);
        vr1 = pm1 ? k : (vr1 == k ? vp : vr1);
        vr2 = pm2 ? k : (vr2 == k ? vp : vr2);
        vr3 = pm3 ? k : (vr3 == k ? vp : vr3);

        // elimination factors (0 for retired/pivot rows)
        const float f0 = (vr0 > k) ? row0[k] * pinv : 0.0f;
        const float f1 = (vr1 > k) ? row1[k] * pinv : 0.0f;
        const float f2 = (vr2 > k) ? row2[k] * pinv : 0.0f;
        const float f3 = (vr3 > k) ? row3[k] * pinv : 0.0f;

        // broadcast pivot row tail, update owned rows
        #pragma unroll
        for (int j = k + 1; j < 16; ++j) {
            const float vj = pm0 ? row0[j] : pm1 ? row1[j] : pm2 ? row2[j] : row3[j];
            const float pv = __shfl(vj, p);
            row0[j] = fmaf(-f0, pv, row0[j]);
            row1[j] = fmaf(-f1, pv, row1[j]);
            row2[j] = fmaf(-f2, pv, row2[j]);
            row3[j] = fmaf(-f3, pv, row3[j]);
        }
    }

    // ---- combine: det_d (uniform in quad) dotted with bf ----
    const float detf = sign * (float)det;
    float acc = (l == 0) ? detf * bf[d] : 0.0f;
    acc += __shfl_xor(acc, 4);
    acc += __shfl_xor(acc, 8);
    acc += __shfl_xor(acc, 16);
    acc += __shfl_xor(acc, 32);
    if (lane == 0) out[b] = empty ? 0.0f : acc;
}

extern "C" void kernel_launch(void* const* d_in, const int* in_sizes, int n_in,
                              void* d_out, int out_size, void* d_ws, size_t ws_size,
                              hipStream_t stream) {
    const float* x  = (const float*)d_in[0];
    const float* W1 = (const float*)d_in[1];
    const float* b1 = (const float*)d_in[2];
    const float* W2 = (const float*)d_in[3];
    const float* b2 = (const float*)d_in[4];
    const float* Wg = (const float*)d_in[5];
    const float* bg = (const float*)d_in[6];
    const float* bf = (const float*)d_in[7];
    float* out = (float*)d_out;

    const int B = in_sizes[0] / 64;
    const int blocks = (B + 3) / 4;   // 4 samples (waves) per 256-thread block
    backflow_kernel<<<blocks, 256, 0, stream>>>(x, W1, b1, W2, b2, Wg, bg, bf, out, B);
}